// Round 11
// baseline (369.663 us; speedup 1.0000x reference)
//
#include <hip/hip_runtime.h>
#include <hip/hip_bf16.h>

#define N_NODES 50000
#define N_EDGES 800000
#define F_IN 1024
#define F_MID 256

typedef _Float16 f16;
typedef _Float16 f16x4 __attribute__((ext_vector_type(4)));
typedef _Float16 f16x8 __attribute__((ext_vector_type(8)));
typedef float f32x4 __attribute__((ext_vector_type(4)));

__device__ __forceinline__ void glds16(const f16* g, f16* l) {
    __builtin_amdgcn_global_load_lds(
        (const __attribute__((address_space(1))) unsigned int*)g,
        (__attribute__((address_space(3))) unsigned int*)l, 16, 0, 0);
}

// ---------------- threefry2x32 (JAX-exact, key=(0,42)); verified: bits = x0^x1, ctr=(0,f) ----------------
__device__ __forceinline__ void tf_round(unsigned &x0, unsigned &x1, int r) {
    x0 += x1;
    x1 = (x1 << r) | (x1 >> (32 - r));
    x1 ^= x0;
}

__device__ __forceinline__ int keep_mask(unsigned f) {
    const unsigned ks0 = 0u, ks1 = 42u;
    const unsigned ks2 = ks0 ^ ks1 ^ 0x1BD11BDAu;
    unsigned x0 = 0u + ks0;
    unsigned x1 = f + ks1;
    tf_round(x0,x1,13); tf_round(x0,x1,15); tf_round(x0,x1,26); tf_round(x0,x1,6);
    x0 += ks1; x1 += ks2 + 1u;
    tf_round(x0,x1,17); tf_round(x0,x1,29); tf_round(x0,x1,16); tf_round(x0,x1,24);
    x0 += ks2; x1 += ks0 + 2u;
    tf_round(x0,x1,13); tf_round(x0,x1,15); tf_round(x0,x1,26); tf_round(x0,x1,6);
    x0 += ks0; x1 += ks1 + 3u;
    tf_round(x0,x1,17); tf_round(x0,x1,29); tf_round(x0,x1,16); tf_round(x0,x1,24);
    x0 += ks1; x1 += ks2 + 4u;
    tf_round(x0,x1,13); tf_round(x0,x1,15); tf_round(x0,x1,26); tf_round(x0,x1,6);
    x0 += ks2; x1 += ks0 + 5u;
    return (((x0 ^ x1) >> 31) == 0u);
}

__device__ __forceinline__ int ld_src(const int* ei, int e, int is64) {
    return is64 ? ei[2 * e] : ei[e];
}
__device__ __forceinline__ int ld_dst(const int* ei, int e, int is64) {
    return is64 ? ei[2 * N_EDGES + 2 * e] : ei[N_EDGES + e];
}

// ---------------- prep: zero deg/cursor/counter, dtype-detect, cvt+transpose+swizzle W1 ----------------
// B swizzle for BK=32 pipeline: logical k stored at k ^ ((n&3)<<3) within its 32-half block.
__global__ __launch_bounds__(256) void k_prep(const float* __restrict__ W1, f16* __restrict__ W1T,
                                              const int* __restrict__ ei,
                                              int* deg, int* cursor, int* counter, int* flag) {
    const int tid = threadIdx.x;
    const int gid = blockIdx.x * 256 + tid;
    const int gstr = gridDim.x * 256;
    if (gid < N_NODES) { deg[gid] = 0; cursor[gid] = 0; }
    if (gid == 0) counter[0] = 0;
    if (blockIdx.x == 0) {
        if (tid == 0) flag[0] = 1;            // 1 = int64
        __syncthreads();
        int nz = 0;
        for (int k = tid; k < 1024; k += 256) nz |= (ei[2 * k + 1] != 0);
        if (nz) atomicAnd(flag, 0);
    }
    for (int i = gid; i < F_IN * F_MID; i += gstr) {
        int k = i >> 8, n = i & 255;          // W1 [1024][256]
        W1T[(size_t)n * F_IN + (k ^ ((n & 3) << 3))] = (f16)W1[i];
    }
}

__global__ __launch_bounds__(256) void k_rows(const int* __restrict__ deg, float* __restrict__ dinv,
                                              int* __restrict__ rowst, int* __restrict__ counter) {
    int i = blockIdx.x * 256 + threadIdx.x;
    if (i < N_NODES) {
        dinv[i] = rsqrtf((float)(deg[i] + 1));       // +1 self-loop
        rowst[i] = atomicAdd(counter, deg[i]);
    }
}

__global__ __launch_bounds__(256) void k_fill(const int* __restrict__ ei, const int* __restrict__ rowst,
                                              int* __restrict__ cursor, int* __restrict__ csr,
                                              const int* __restrict__ flag) {
    int e = blockIdx.x * 256 + threadIdx.x;
    int is64 = flag[0];
    if (e < N_EDGES) {
        int d = ld_dst(ei, e, is64);
        int pos = rowst[d] + atomicAdd(&cursor[d], 1);
        csr[pos] = ld_src(ei, e, is64);
    }
}

// ---------------- MFMA f16 GEMM: BK=32, 4-slot LDS, 3-ahead counted-vmcnt pipeline (T4) ----------------
// C[M,Ntot] = A[M,K] @ BT[Ntot,K]^T.  BT pre-swizzled (k ^ ((n&3)<<3) per 32-half block).
// A reg-staged (f16x4 if A16 else f32x4 NT + cvt) -> swizzled ds_write.
// Per stage per wave: 1 A-load + 2 B-glds = 3 vmem ops (uniform).  Waits: vmcnt(6) steady state.
// C16: f16 out unscaled; else f32 + bias (LDS-transposed contiguous stores, NT).
// Riders (blockIdx.x >= mainx): edge-degree count + W2 cvt+transpose+swizzle.
template<int BM, int BN, int TN, int K, bool A16, bool C16>
__global__ __launch_bounds__(TN, 4) void k_mfma(const void* __restrict__ Ag,
                                                const f16* __restrict__ BTg,
                                                void* __restrict__ Cg,
                                                const float* __restrict__ bias,
                                                int M, int Ntot, int mainx,
                                                const int* __restrict__ ei, int* __restrict__ deg,
                                                const int* __restrict__ flag,
                                                const float* __restrict__ Wr, f16* __restrict__ WrT) {
    if ((int)blockIdx.x >= mainx) {
        const int str = (gridDim.x - mainx) * TN;
        const int t0 = (blockIdx.x - mainx) * TN + threadIdx.x;
        const int is64 = flag[0];
        for (int e = t0; e < N_EDGES; e += str)
            atomicAdd(&deg[ld_dst(ei, e, is64)], 1);
        for (int i = t0; i < F_MID * F_IN; i += str) {
            int k = i >> 10, n = i & 1023;    // Wr [256][1024]
            WrT[(size_t)n * F_MID + (k ^ ((n & 3) << 3))] = (f16)Wr[i];
        }
        return;
    }

    constexpr int BK = 32;
    constexpr int NKT = K / BK;
    static_assert(NKT % 4 == 0 && NKT >= 8, "pipeline needs NKT multiple of 4");
    constexpr int NW = TN / 64;           // 8
    constexpr int WTN = BN / NW;          // 32
    constexpr int FN = WTN / 16;          // 2
    constexpr int ASLOT = BM * BK;        // 2048
    constexpr int BSLOT = BN * BK;        // 8192
    constexpr int BCH = BSLOT / 512 / NW; // 2 glds per wave per stage
    constexpr int SMEM_STG = (4 * ASLOT + 4 * BSLOT) * 2;   // 80 KB
    constexpr int LDC = BN + 8;
    constexpr int SMEM_EPI = BM * LDC * (C16 ? 2 : 4);
    constexpr int SMEM_SZ = SMEM_STG > SMEM_EPI ? SMEM_STG : SMEM_EPI;
    __shared__ __align__(16) char smem[SMEM_SZ];
    f16* As_ = (f16*)smem;
    f16* Bs_ = As_ + 4 * ASLOT;

    const int tid = threadIdx.x, lane = tid & 63, wid = tid >> 6;
    const int l15 = lane & 15, g8 = (lane >> 4) * 8;
    const int row0 = blockIdx.x * BM, col0 = blockIdx.y * BN;
    const int ar = tid >> 3;              // A staging: 8 thr/row (TN == BM*8)
    const int ac = (tid & 7) * 4;         // 4 elems (floats or halves)

    f32x4 acc[4][FN] = {};
    f32x4 av0q = {}, av1q = {}, av2q = {}, av3q = {};
    f16x4 av0h = {}, av1h = {}, av2h = {}, av3h = {};

#define ISSUE(T, S) do {                                                            \
    const int k0_ = (T) * BK;                                                       \
    const int gr_ = row0 + ar;                                                      \
    if constexpr (A16) {                                                            \
        const f16* A_ = (const f16*)Ag;                                             \
        av##S##h = (gr_ < M) ? *(const f16x4*)&A_[(size_t)gr_ * K + k0_ + ac]       \
                             : (f16x4){};                                           \
    } else {                                                                        \
        const float* A_ = (const float*)Ag;                                         \
        av##S##q = (gr_ < M) ? __builtin_nontemporal_load(                          \
                                   (const f32x4*)&A_[(size_t)gr_ * K + k0_ + ac])   \
                             : (f32x4){};                                           \
    }                                                                               \
    _Pragma("unroll")                                                               \
    for (int j_ = 0; j_ < BCH; ++j_) {                                              \
        int ci_ = wid * BCH + j_;                                                   \
        int li_ = ci_ * 512 + lane * 8;                                             \
        int r_ = li_ >> 5, c_ = li_ & 31;                                           \
        glds16(&BTg[(size_t)(col0 + r_) * K + k0_ + c_], &Bs_[(S) * BSLOT + ci_ * 512]); \
    }                                                                               \
} while (0)

#define AWRITE(S) do {                                                              \
    f16x4 h_;                                                                       \
    if constexpr (A16) h_ = av##S##h;                                               \
    else h_ = __builtin_convertvector(av##S##q, f16x4);                             \
    *(f16x4*)&As_[(S) * ASLOT + ar * BK + (ac ^ ((ar & 3) << 3))] = h_;             \
} while (0)

#define COMPUTE(S) do {                                                             \
    f16x8 af_[4], bf_[FN];                                                          \
    _Pragma("unroll")                                                               \
    for (int m_ = 0; m_ < 4; ++m_) {                                                \
        int r_ = m_ * 16 + l15;                                                     \
        af_[m_] = *(const f16x8*)&As_[(S) * ASLOT + r_ * BK + (g8 ^ ((r_ & 3) << 3))]; \
    }                                                                               \
    _Pragma("unroll")                                                               \
    for (int n_ = 0; n_ < FN; ++n_) {                                               \
        int r_ = wid * WTN + n_ * 16 + l15;                                         \
        bf_[n_] = *(const f16x8*)&Bs_[(S) * BSLOT + r_ * BK + (g8 ^ ((r_ & 3) << 3))]; \
    }                                                                               \
    _Pragma("unroll")                                                               \
    for (int m_ = 0; m_ < 4; ++m_)                                                  \
        _Pragma("unroll")                                                           \
        for (int n_ = 0; n_ < FN; ++n_)                                             \
            acc[m_][n_] = __builtin_amdgcn_mfma_f32_16x16x32_f16(af_[m_], bf_[n_], acc[m_][n_], 0, 0, 0); \
} while (0)

#define PBAR() do { __builtin_amdgcn_sched_barrier(0); __builtin_amdgcn_s_barrier(); \
                    __builtin_amdgcn_sched_barrier(0); } while (0)
#define VMW6() asm volatile("s_waitcnt vmcnt(6) lgkmcnt(0)" ::: "memory")
#define VMW3() asm volatile("s_waitcnt vmcnt(3) lgkmcnt(0)" ::: "memory")
#define VMW0() asm volatile("s_waitcnt vmcnt(0) lgkmcnt(0)" ::: "memory")

#define STEP(T, RD, WR, IS) do {                                                    \
    if ((T) + 3 < NKT) ISSUE((T) + 3, IS);                                          \
    COMPUTE(RD);                                                                    \
    if ((T) + 1 < NKT) AWRITE(WR);                                                  \
    if ((T) < NKT - 3) VMW6();                                                      \
    else if ((T) == NKT - 3) VMW3();                                                \
    else if ((T) == NKT - 2) VMW0();                                                \
    if ((T) < NKT - 1) PBAR();                                                      \
} while (0)

    // prologue: stages 0,1,2 issued; A(0) written; stage-0 B complete; barrier.
    ISSUE(0, 0); ISSUE(1, 1); ISSUE(2, 2);
    AWRITE(0);
    VMW6(); PBAR();

#pragma unroll
    for (int g = 0; g < NKT / 4; ++g) {
        const int t0 = g * 4;
        STEP(t0 + 0, 0, 1, 3);
        STEP(t0 + 1, 1, 2, 0);
        STEP(t0 + 2, 2, 3, 1);
        STEP(t0 + 3, 3, 0, 2);
    }
    VMW0();
    __syncthreads();

#undef ISSUE
#undef AWRITE
#undef COMPUTE
#undef PBAR
#undef VMW6
#undef VMW3
#undef VMW0
#undef STEP

    // ---- epilogue: acc -> LDS (stride LDC) -> contiguous vector stores ----
    // C/D frag mapping: col=lane&15, row=(lane>>4)*4+reg
    if constexpr (C16) {
        f16* CT = (f16*)smem;
        #pragma unroll
        for (int m = 0; m < 4; ++m)
            #pragma unroll
            for (int j = 0; j < 4; ++j) {
                const int rl = m * 16 + (lane >> 4) * 4 + j;
                #pragma unroll
                for (int n = 0; n < FN; ++n)
                    CT[rl * LDC + wid * WTN + n * 16 + l15] = (f16)acc[m][n][j];
            }
        __syncthreads();
        f16* C = (f16*)Cg;
        constexpr int NCH = BM * BN / 8;
        #pragma unroll
        for (int ci = tid; ci < NCH; ci += TN) {
            const int r = ci / (BN / 8), c = (ci % (BN / 8)) * 8;
            const int gr = row0 + r;
            if (gr < M) {
                f16x8 v = *(const f16x8*)&CT[r * LDC + c];
                *(f16x8*)&C[(size_t)gr * Ntot + col0 + c] = v;
            }
        }
    } else {
        float* CT = (float*)smem;
        #pragma unroll
        for (int m = 0; m < 4; ++m)
            #pragma unroll
            for (int j = 0; j < 4; ++j) {
                const int rl = m * 16 + (lane >> 4) * 4 + j;
                #pragma unroll
                for (int n = 0; n < FN; ++n)
                    CT[rl * LDC + wid * WTN + n * 16 + l15] = acc[m][n][j];
            }
        __syncthreads();
        float* C = (float*)Cg;
        constexpr int NCH = BM * BN / 4;
        #pragma unroll
        for (int ci = tid; ci < NCH; ci += TN) {
            const int r = ci / (BN / 4), c = (ci % (BN / 4)) * 4;
            const int gr = row0 + r;
            if (gr < M) {
                f32x4 v = *(const f32x4*)&CT[r * LDC + c];
                v += *(const f32x4*)&bias[col0 + c];
                __builtin_nontemporal_store(v, (f32x4*)&C[(size_t)gr * Ntot + col0 + c]);
            }
        }
    }
}

// ---------------- aggregation (wave per row, unroll-8 gather) ----------------
// SCALED_IN=1: rows carry dinv[src] -> acc = hin[row] + sum hin[s]
// SCALED_IN=0: unscaled             -> acc = dinv[row]*hin[row] + sum dinv[s]*hin[s]
// Then *= dinv[row].  POST: +b1, relu, dropout, *dinv[row].
template<int POST, int SCALED_IN>
__global__ __launch_bounds__(256) void k_agg16(const f16* __restrict__ hin,
                                               f16* __restrict__ hout,
                                               const int* __restrict__ csr,
                                               const int* __restrict__ rowst,
                                               const int* __restrict__ deg,
                                               const float* __restrict__ dinv,
                                               const float* __restrict__ bias) {
    const int wid = threadIdx.x >> 6;
    const int lane = threadIdx.x & 63;
    const int row = blockIdx.x * 4 + wid;
    const int start = rowst[row];
    const int cnt = deg[row];
    const int ch = lane * 4;
    const float di = dinv[row];

    f32x4 acc = __builtin_convertvector(*(const f16x4*)&hin[(size_t)row * F_MID + ch], f32x4);
    if (!SCALED_IN) acc *= di;
    int k = 0;
    for (; k + 8 <= cnt; k += 8) {
        int s[8];
        f16x4 v[8];
        #pragma unroll
        for (int u = 0; u < 8; ++u) s[u] = csr[start + k + u];
        #pragma unroll
        for (int u = 0; u < 8; ++u) v[u] = *(const f16x4*)&hin[(size_t)s[u] * F_MID + ch];
        if (SCALED_IN) {
            #pragma unroll
            for (int u = 0; u < 8; ++u) acc += __builtin_convertvector(v[u], f32x4);
        } else {
            #pragma unroll
            for (int u = 0; u < 8; ++u) acc += dinv[s[u]] * __builtin_convertvector(v[u], f32x4);
        }
    }
    for (; k < cnt; ++k) {
        const int s = csr[start + k];
        f32x4 v = __builtin_convertvector(*(const f16x4*)&hin[(size_t)s * F_MID + ch], f32x4);
        acc += SCALED_IN ? v : dinv[s] * v;
    }
    acc *= di;

    if (POST) {
        const unsigned f0 = (unsigned)row * F_MID + (unsigned)ch;
        #pragma unroll
        for (int j = 0; j < 4; ++j) {
            float t = acc[j] + bias[ch + j];
            t = fmaxf(t, 0.0f);
            t = keep_mask(f0 + j) ? t * 2.0f : 0.0f;
            acc[j] = t * di;
        }
    }
    *(f16x4*)&hout[(size_t)row * F_MID + ch] = __builtin_convertvector(acc, f16x4);
}

// ---------------- launch ----------------
extern "C" void kernel_launch(void* const* d_in, const int* in_sizes, int n_in,
                              void* d_out, int out_size, void* d_ws, size_t ws_size,
                              hipStream_t stream) {
    const float* x  = (const float*)d_in[0];
    const int*   ei = (const int*)d_in[1];
    const float* W1 = (const float*)d_in[2];
    const float* b1 = (const float*)d_in[3];
    const float* W2 = (const float*)d_in[4];
    const float* b2 = (const float*)d_in[5];
    float* out = (float*)d_out;

    // d_out doubles as fp16 scratch (dead before the final f32 overwrite):
    f16* h0 = (f16*)out;                               // [N,256] xW1, unscaled, linear
    f16* h1s = h0 + (size_t)N_NODES * F_MID;           // [N,256] post relu/dropout, dinv-scaled, linear

    // workspace
    f16*   h2agg = (f16*)d_ws;                         // [N,256] agg2 out, LINEAR (GEMM2 reg-stages A)
    f16*   W1T   = h2agg + (size_t)(N_NODES + 64) * F_MID;  // [256][1024] swizzled (BK=32 pattern)
    f16*   W2T   = W1T + (size_t)F_MID * F_IN;         // [1024][256] swizzled
    float* dinv  = (float*)(W2T + (size_t)F_IN * F_MID);
    int*   deg   = (int*)(dinv + N_NODES);
    int*   rowst = deg + N_NODES;
    int*   cursor= rowst + N_NODES;
    int*   csr   = cursor + N_NODES;
    int*   counter = csr + N_EDGES;
    int*   flag    = counter + 1;

    // 1) prep: zero counters, dtype detect, W1 -> W1T (swizzled)
    k_prep<<<256, 256, 0, stream>>>(W1, W1T, ei, deg, cursor, counter, flag);

    // 2) GEMM1 (+riders: edge-degree count, W2 -> W2T): h0 = x @ W1
    {
        const int mainx = (N_NODES + 63) / 64;         // 782
        dim3 grid(mainx + 240, 1);
        k_mfma<64, 256, 512, 1024, false, true><<<grid, 512, 0, stream>>>(
            (const void*)x, W1T, (void*)h0, nullptr, N_NODES, F_MID,
            mainx, ei, deg, flag, W2, W2T);
    }

    // 3) rows (dinv, rowst), 4) fill (csr)
    k_rows<<<(N_NODES + 255) / 256, 256, 0, stream>>>(deg, dinv, rowst, counter);
    k_fill<<<(N_EDGES + 255) / 256, 256, 0, stream>>>(ei, rowst, cursor, csr, flag);

    // 5) agg1: dinv-weighted gather; +b1, relu, dropout, pre-scale.  6) agg2: linear out.
    k_agg16<1, 0><<<N_NODES / 4, 256, 0, stream>>>(h0, h1s, csr, rowst, deg, dinv, b1);
    k_agg16<0, 1><<<N_NODES / 4, 256, 0, stream>>>(h1s, h2agg, csr, rowst, deg, dinv, nullptr);

    // 7) GEMM2: out = h2agg @ W2 + b2.  BM=64, BN=256, grid (782,4).
    {
        const int mainx = (N_NODES + 63) / 64;
        dim3 grid(mainx, 4);
        k_mfma<64, 256, 512, 256, true, false><<<grid, 512, 0, stream>>>(
            (const void*)h2agg, W2T, (void*)out, b2, N_NODES, F_IN,
            mainx, ei, deg, flag, W2, W2T);
    }
}